// Round 1
// baseline (56.861 us; speedup 1.0000x reference)
//
#include <hip/hip_runtime.h>
#include <math.h>

#define L 512
#define TILE_T 16
#define NTHREADS 256

static constexpr float EPS = 1e-6f;
static constexpr float INV_SQRT_2PI = 0.39894228040143267794f;

__global__ __launch_bounds__(NTHREADS) void ge_kernel(
    const float* __restrict__ text,  // [B, L, D]
    const int*   __restrict__ durs,  // [B, L]
    float*       __restrict__ out,   // [B, T, D]
    int B, int D, int T, int tilesPerB)
{
    __shared__ float s_mean[L];
    __shared__ float s_isig[L];
    __shared__ float s_probs[TILE_T][L];
    __shared__ float s_norm[TILE_T];
    __shared__ float s_ts[NTHREADS];
    __shared__ int   s_rowactive[L];
    __shared__ int   s_lmin, s_lmax;
    __shared__ float s_red[4];

    const int tid = threadIdx.x;
    const int blk = blockIdx.x;
    const int b   = blk / tilesPerB;
    const int t0  = (blk % tilesPerB) * TILE_T;

    // ---- stage 0: load durs, inclusive cumsum over L, derive mean / 1/sigma ----
    const int l0 = 2 * tid;
    const float d0 = (float)durs[b * L + l0];
    const float d1 = (float)durs[b * L + l0 + 1];
    const float pairsum = d0 + d1;

    s_ts[tid] = pairsum;
    __syncthreads();
    #pragma unroll
    for (int off = 1; off < NTHREADS; off <<= 1) {
        float v = s_ts[tid];
        float a = (tid >= off) ? s_ts[tid - off] : 0.0f;
        __syncthreads();
        s_ts[tid] = v + a;
        __syncthreads();
    }
    const float excl = s_ts[tid] - pairsum;   // exclusive prefix of this thread's pair

    const float cum0 = excl + d0;             // inclusive cumsum at l0
    const float cum1 = excl + d0 + d1;        // inclusive cumsum at l0+1

    const float sig0 = d0 * 0.5f + EPS;       // d / SIGMA_C + EPS, SIGMA_C = 2
    const float sig1 = d1 * 0.5f + EPS;

    s_mean[l0]     = cum0 + d0 * 0.5f;
    s_mean[l0 + 1] = cum1 + d1 * 0.5f;
    s_isig[l0]     = 1.0f / sig0;
    s_isig[l0 + 1] = 1.0f / sig1;
    s_rowactive[l0]     = 0;
    s_rowactive[l0 + 1] = 0;
    if (tid == 0) { s_lmin = L; s_lmax = -1; }
    __syncthreads();

    // ---- stage 1: probs for TILE_T time steps, per-t sum, nonzero window ----
    int myLmin = L, myLmax = -1;
    for (int tt = 0; tt < TILE_T; ++tt) {
        const float tf = (float)(t0 + tt) + 0.5f;
        float part = 0.0f;
        #pragma unroll
        for (int half = 0; half < 2; ++half) {
            const int l = tid + half * NTHREADS;
            const float z = (tf - s_mean[l]) * s_isig[l];
            const float p = __expf(-0.5f * z * z) * s_isig[l] * INV_SQRT_2PI;
            s_probs[tt][l] = p;
            part += p;
            if (p > 0.0f) {
                myLmin = min(myLmin, l);
                myLmax = max(myLmax, l);
                s_rowactive[l] = 1;
            }
        }
        // block reduction of part
        #pragma unroll
        for (int off = 32; off > 0; off >>= 1) part += __shfl_down(part, off);
        const int wid = tid >> 6;
        if ((tid & 63) == 0) s_red[wid] = part;
        __syncthreads();
        if (tid == 0) {
            const float s = s_red[0] + s_red[1] + s_red[2] + s_red[3];
            s_norm[tt] = 1.0f / (s + EPS);
        }
        __syncthreads();
    }
    atomicMin(&s_lmin, myLmin);
    atomicMax(&s_lmax, myLmax);
    __syncthreads();

    const int lmin = s_lmin;
    const int lmax = s_lmax;

    // ---- stage 2: weighted accumulation over active rows (thread owns d = tid) ----
    float acc[TILE_T];
    #pragma unroll
    for (int i = 0; i < TILE_T; ++i) acc[i] = 0.0f;

    const float* trow = text + (size_t)b * L * D + tid;
    for (int l = lmin; l <= lmax; ++l) {
        if (s_rowactive[l]) {
            const float val = trow[(size_t)l * D];
            #pragma unroll
            for (int tt = 0; tt < TILE_T; ++tt) acc[tt] += s_probs[tt][l] * val;
        }
    }

    // ---- stage 3: normalize + store ----
    const size_t obase = ((size_t)b * T + t0) * D + tid;
    #pragma unroll
    for (int tt = 0; tt < TILE_T; ++tt) {
        if (t0 + tt < T) out[obase + (size_t)tt * D] = acc[tt] * s_norm[tt];
    }
}

extern "C" void kernel_launch(void* const* d_in, const int* in_sizes, int n_in,
                              void* d_out, int out_size, void* d_ws, size_t ws_size,
                              hipStream_t stream) {
    const float* text = (const float*)d_in[0];
    const int*   durs = (const int*)d_in[1];
    float*       out  = (float*)d_out;

    const int BL = in_sizes[1];        // B * L
    const int D  = in_sizes[0] / BL;   // 256
    const int B  = BL / L;             // 16
    const int T  = out_size / (B * D); // 2048
    const int tilesPerB = (T + TILE_T - 1) / TILE_T;

    ge_kernel<<<dim3(B * tilesPerB), dim3(NTHREADS), 0, stream>>>(
        text, durs, out, B, D, T, tilesPerB);
}

// Round 2
// 25.554 us; speedup vs baseline: 2.2252x; 2.2252x over previous
//
#include <hip/hip_runtime.h>
#include <math.h>

#define L 512
#define TILE_T 16
#define NTHREADS 256
#define CAP 64            // window rows staged in LDS per chunk
#define ZWIN 14.5f        // fp32 exp underflow (incl. denormals) at |z| ~ 14.4

static constexpr float EPS = 1e-6f;
static constexpr float INV_SQRT_2PI = 0.39894228040143267794f;

__global__ __launch_bounds__(NTHREADS) void ge_kernel(
    const float* __restrict__ text,  // [B, L, D]
    const int*   __restrict__ durs,  // [B, L]
    float*       __restrict__ out,   // [B, T, D]
    int B, int D, int T, int tilesPerB)
{
    __shared__ float s_mean[L];
    __shared__ float s_isig[L];
    __shared__ float s_probs[CAP][TILE_T];   // [row][tt] -> float4-readable
    __shared__ float s_wtot[4];
    __shared__ float s_wsum[4][TILE_T];
    __shared__ float s_norm[TILE_T];
    __shared__ int   s_lminmax[2];

    const int tid  = threadIdx.x;
    const int lane = tid & 63;
    const int wid  = tid >> 6;
    const int blk  = blockIdx.x;
    const int b    = blk / tilesPerB;
    const int t0   = (blk % tilesPerB) * TILE_T;

    // ---- stage 0: durs -> cumsum (wave-shuffle scan) -> mean, 1/sigma ----
    const int l0 = 2 * tid;
    const float d0 = (float)durs[b * L + l0];
    const float d1 = (float)durs[b * L + l0 + 1];
    const float pairsum = d0 + d1;

    float v = pairsum;
    #pragma unroll
    for (int off = 1; off < 64; off <<= 1) {
        float n = __shfl_up(v, off, 64);
        if (lane >= off) v += n;
    }
    if (lane == 63) s_wtot[wid] = v;
    if (tid == 0) { s_lminmax[0] = L; s_lminmax[1] = -1; }
    __syncthreads();
    float wpre = 0.f;
    for (int w = 0; w < wid; ++w) wpre += s_wtot[w];
    const float excl = wpre + v - pairsum;   // cumsum before row l0

    const float cum0  = excl + d0;
    const float cum1  = cum0 + d1;
    const float mean0 = cum0 + 0.5f * d0;
    const float mean1 = cum1 + 0.5f * d1;
    const float sig0  = 0.5f * d0 + EPS;
    const float sig1  = 0.5f * d1 + EPS;
    s_mean[l0]   = mean0;  s_mean[l0+1] = mean1;
    s_isig[l0]   = 1.0f / sig0;
    s_isig[l0+1] = 1.0f / sig1;

    // ---- analytic active window: rows with d>=1 and mean +- Z*sigma hitting the t-tile ----
    const float tlo = (float)t0 + 0.5f;
    const float thi = (float)t0 + (float)TILE_T - 0.5f;
    int myMin = L, myMax = -1;
    if (d0 >= 1.f) {
        const float r = ZWIN * sig0;
        if (mean0 + r >= tlo && mean0 - r <= thi) { myMin = l0;  myMax = l0; }
    }
    if (d1 >= 1.f) {
        const float r = ZWIN * sig1;
        if (mean1 + r >= tlo && mean1 - r <= thi) { myMin = min(myMin, l0+1); myMax = max(myMax, l0+1); }
    }
    #pragma unroll
    for (int off = 32; off > 0; off >>= 1) {
        myMin = min(myMin, __shfl_xor(myMin, off, 64));
        myMax = max(myMax, __shfl_xor(myMax, off, 64));
    }
    if (lane == 0) {
        atomicMin(&s_lminmax[0], myMin);
        atomicMax(&s_lminmax[1], myMax);
    }
    __syncthreads();
    const int lmin = s_lminmax[0];
    const int lmax = s_lminmax[1];

    // ---- stages 1+2 chunked over the window ----
    float acc[TILE_T];
    #pragma unroll
    for (int i = 0; i < TILE_T; ++i) acc[i] = 0.f;
    float psum = 0.f;                       // partial norm-sum for tt = tid & 15
    const int   mytt = tid & 15;
    const float myt  = (float)(t0 + mytt) + 0.5f;
    const float* trow = text + (size_t)b * L * D + tid;   // tid == d (D == 256)

    for (int base = lmin; base <= lmax; base += CAP) {
        const int nr = min(CAP, lmax - base + 1);
        const int total = nr * TILE_T;
        // evaluate probs for window rows only; each thread keeps tt = tid&15
        for (int idx = tid; idx < total; idx += NTHREADS) {
            const int row = idx >> 4;               // (idx & 15) == mytt
            const int l   = base + row;
            const float z = (myt - s_mean[l]) * s_isig[l];
            const float p = __expf(-0.5f * z * z) * s_isig[l] * INV_SQRT_2PI;
            s_probs[row][mytt] = p;
            psum += p;
        }
        __syncthreads();
        // branch-free weighted accumulation (d=0 rows have p == 0 exactly)
        const float4* sp = (const float4*)&s_probs[0][0];
        #pragma unroll 2
        for (int i = 0; i < nr; ++i) {
            const float val = trow[(size_t)(base + i) * D];
            const float4 p0 = sp[i*4+0];
            const float4 p1 = sp[i*4+1];
            const float4 p2 = sp[i*4+2];
            const float4 p3 = sp[i*4+3];
            acc[0]  += p0.x * val; acc[1]  += p0.y * val; acc[2]  += p0.z * val; acc[3]  += p0.w * val;
            acc[4]  += p1.x * val; acc[5]  += p1.y * val; acc[6]  += p1.z * val; acc[7]  += p1.w * val;
            acc[8]  += p2.x * val; acc[9]  += p2.y * val; acc[10] += p2.z * val; acc[11] += p2.w * val;
            acc[12] += p3.x * val; acc[13] += p3.y * val; acc[14] += p3.z * val; acc[15] += p3.w * val;
        }
        __syncthreads();
    }

    // ---- reduce the 16 norm-sums (lanes with same tid&15), then normalize + store ----
    psum += __shfl_xor(psum, 16, 64);
    psum += __shfl_xor(psum, 32, 64);
    if (lane < 16) s_wsum[wid][lane] = psum;
    __syncthreads();
    if (tid < TILE_T) {
        const float s = s_wsum[0][tid] + s_wsum[1][tid] + s_wsum[2][tid] + s_wsum[3][tid];
        s_norm[tid] = 1.0f / (s + EPS);
    }
    __syncthreads();

    const size_t obase = ((size_t)b * T + t0) * D + tid;
    #pragma unroll
    for (int tt = 0; tt < TILE_T; ++tt) {
        if (t0 + tt < T) out[obase + (size_t)tt * D] = acc[tt] * s_norm[tt];
    }
}

extern "C" void kernel_launch(void* const* d_in, const int* in_sizes, int n_in,
                              void* d_out, int out_size, void* d_ws, size_t ws_size,
                              hipStream_t stream) {
    const float* text = (const float*)d_in[0];
    const int*   durs = (const int*)d_in[1];
    float*       out  = (float*)d_out;

    const int BL = in_sizes[1];        // B * L
    const int D  = in_sizes[0] / BL;   // 256
    const int B  = BL / L;             // 16
    const int T  = out_size / (B * D); // 2048
    const int tilesPerB = (T + TILE_T - 1) / TILE_T;

    ge_kernel<<<dim3(B * tilesPerB), dim3(NTHREADS), 0, stream>>>(
        text, durs, out, B, D, T, tilesPerB);
}

// Round 3
// 18.161 us; speedup vs baseline: 3.1309x; 1.4070x over previous
//
#include <hip/hip_runtime.h>
#include <math.h>

#define L 512
#define TILE_T 16
#define NTHREADS 256
#define NACT_MAX 160      // provable bound: active means spaced >=1 in a 116.5-unit interval -> <=117
#define ZWIN 14.5f        // fp32 exp (incl. denormals) underflows at |z| ~ 14.37

static constexpr float EPS = 1e-6f;
static constexpr float INV_SQRT_2PI = 0.39894228040143267794f;

__global__ __launch_bounds__(NTHREADS, 8) void ge_kernel(
    const float* __restrict__ text,  // [B, L, D]
    const int*   __restrict__ durs,  // [B, L]
    float*       __restrict__ out,   // [B, T, D]
    int B, int D, int T, int tilesPerB)
{
    __shared__ float s_lmean[NACT_MAX];
    __shared__ float s_lisig[NACT_MAX];
    __shared__ int   s_lrow[NACT_MAX];
    __shared__ float s_probs[NACT_MAX][TILE_T];
    __shared__ float s_wtot[4];
    __shared__ int   s_wcnt[4];
    __shared__ float s_wsum[4][TILE_T];
    __shared__ float s_norm[TILE_T];

    const int tid  = threadIdx.x;
    const int lane = tid & 63;
    const int wid  = tid >> 6;
    const int blk  = blockIdx.x;
    const int b    = blk / tilesPerB;
    const int t0   = (blk % tilesPerB) * TILE_T;

    // ---- stage 0: durs -> cumsum (wave scan) -> mean, 1/sigma; build active-row list ----
    const int l0 = 2 * tid;
    const float d0 = (float)durs[b * L + l0];
    const float d1 = (float)durs[b * L + l0 + 1];
    const float pairsum = d0 + d1;

    float v = pairsum;
    #pragma unroll
    for (int off = 1; off < 64; off <<= 1) {
        float n = __shfl_up(v, off, 64);
        if (lane >= off) v += n;
    }
    if (lane == 63) s_wtot[wid] = v;
    __syncthreads();
    float wpre = 0.f;
    for (int w = 0; w < wid; ++w) wpre += s_wtot[w];
    const float excl = wpre + v - pairsum;    // cumsum before row l0

    const float cum0  = excl + d0;
    const float cum1  = cum0 + d1;
    const float mean0 = cum0 + 0.5f * d0;
    const float mean1 = cum1 + 0.5f * d1;
    const float sig0  = 0.5f * d0 + EPS;
    const float sig1  = 0.5f * d1 + EPS;
    const float isig0 = 1.0f / sig0;
    const float isig1 = 1.0f / sig1;

    const float tlo = (float)t0 + 0.5f;
    const float thi = (float)t0 + (float)TILE_T - 0.5f;
    const float r0 = ZWIN * sig0;
    const float r1 = ZWIN * sig1;
    const bool act0 = (d0 >= 1.f) && (mean0 + r0 >= tlo) && (mean0 - r0 <= thi);
    const bool act1 = (d1 >= 1.f) && (mean1 + r1 >= tlo) && (mean1 - r1 <= thi);

    const unsigned long long m0 = __ballot(act0);
    const unsigned long long m1 = __ballot(act1);
    const unsigned long long lt = (lane == 0) ? 0ull : ((~0ull) >> (64 - lane));
    const int off_in_wave = __popcll(m0 & lt) + __popcll(m1 & lt);
    const int cnt_wave = __popcll(m0) + __popcll(m1);
    if (lane == 0) s_wcnt[wid] = cnt_wave;
    __syncthreads();
    int base_w = 0;
    for (int w = 0; w < wid; ++w) base_w += s_wcnt[w];
    const int nact = s_wcnt[0] + s_wcnt[1] + s_wcnt[2] + s_wcnt[3];

    if (act0) {
        const int i = base_w + off_in_wave;
        s_lrow[i] = l0; s_lmean[i] = mean0; s_lisig[i] = isig0;
    }
    if (act1) {
        const int i = base_w + off_in_wave + (act0 ? 1 : 0);
        s_lrow[i] = l0 + 1; s_lmean[i] = mean1; s_lisig[i] = isig1;
    }
    __syncthreads();

    // ---- stage 1: probs for listed rows; per-t norm sums ----
    float psum = 0.f;                         // partial for tt = tid & 15
    const int   mytt = tid & 15;
    const float myt  = (float)(t0 + mytt) + 0.5f;
    const int total = nact * TILE_T;
    for (int idx = tid; idx < total; idx += NTHREADS) {
        const int i = idx >> 4;               // (idx & 15) == mytt
        const float z = (myt - s_lmean[i]) * s_lisig[i];
        const float p = __expf(-0.5f * z * z) * s_lisig[i] * INV_SQRT_2PI;
        s_probs[i][mytt] = p;
        psum += p;
    }
    psum += __shfl_xor(psum, 16, 64);
    psum += __shfl_xor(psum, 32, 64);
    if (lane < 16) s_wsum[wid][lane] = psum;
    __syncthreads();
    if (tid < TILE_T) {
        const float s = s_wsum[0][tid] + s_wsum[1][tid] + s_wsum[2][tid] + s_wsum[3][tid];
        s_norm[tid] = 1.0f / (s + EPS);
    }
    __syncthreads();

    // ---- stage 2: wave wid owns tt = 4*wid..4*wid+3; thread owns d-quad lane*4 ----
    float4 a0 = {0,0,0,0}, a1 = {0,0,0,0}, a2 = {0,0,0,0}, a3 = {0,0,0,0};
    const float* tbase = text + (size_t)b * L * D + (lane << 2);
    #pragma unroll 2
    for (int i = 0; i < nact; ++i) {
        const int l = s_lrow[i];
        const float4 val = *(const float4*)(tbase + (size_t)l * D);
        const float4 p   = *(const float4*)&s_probs[i][wid << 2];  // wave-uniform broadcast
        a0.x += p.x * val.x; a0.y += p.x * val.y; a0.z += p.x * val.z; a0.w += p.x * val.w;
        a1.x += p.y * val.x; a1.y += p.y * val.y; a1.z += p.y * val.z; a1.w += p.y * val.w;
        a2.x += p.z * val.x; a2.y += p.z * val.y; a2.z += p.z * val.z; a2.w += p.z * val.w;
        a3.x += p.w * val.x; a3.y += p.w * val.y; a3.z += p.w * val.z; a3.w += p.w * val.w;
    }

    // ---- stage 3: normalize + store (wave stores 4 consecutive t rows) ----
    const float4 nrm = *(const float4*)&s_norm[wid << 2];
    const int tt0 = t0 + (wid << 2);
    float* obase = out + ((size_t)b * T + tt0) * D + (lane << 2);
    if (tt0 + 0 < T) { float4 o = {a0.x*nrm.x, a0.y*nrm.x, a0.z*nrm.x, a0.w*nrm.x}; *(float4*)(obase + 0*(size_t)D) = o; }
    if (tt0 + 1 < T) { float4 o = {a1.x*nrm.y, a1.y*nrm.y, a1.z*nrm.y, a1.w*nrm.y}; *(float4*)(obase + 1*(size_t)D) = o; }
    if (tt0 + 2 < T) { float4 o = {a2.x*nrm.z, a2.y*nrm.z, a2.z*nrm.z, a2.w*nrm.z}; *(float4*)(obase + 2*(size_t)D) = o; }
    if (tt0 + 3 < T) { float4 o = {a3.x*nrm.w, a3.y*nrm.w, a3.z*nrm.w, a3.w*nrm.w}; *(float4*)(obase + 3*(size_t)D) = o; }
}

extern "C" void kernel_launch(void* const* d_in, const int* in_sizes, int n_in,
                              void* d_out, int out_size, void* d_ws, size_t ws_size,
                              hipStream_t stream) {
    const float* text = (const float*)d_in[0];
    const int*   durs = (const int*)d_in[1];
    float*       out  = (float*)d_out;

    const int BL = in_sizes[1];        // B * L
    const int D  = in_sizes[0] / BL;   // 256
    const int B  = BL / L;             // 16
    const int T  = out_size / (B * D); // 2048
    const int tilesPerB = (T + TILE_T - 1) / TILE_T;

    ge_kernel<<<dim3(B * tilesPerB), dim3(NTHREADS), 0, stream>>>(
        text, durs, out, B, D, T, tilesPerB);
}